// Round 5
// baseline (1139.865 us; speedup 1.0000x reference)
//
#include <hip/hip_runtime.h>
#include <hip/hip_bf16.h>
#include <math.h>

// Problem constants
#define B_SZ 8
#define N_SZ 4096
#define C_SZ 128
#define K_SZ 16
#define NPOINT 1024            // N / POOL_RATE

// FPS config: 256 threads (4 waves, 1 per SIMD), 16 CONTIGUOUS points/thread.
// (r4 proved 2 waves/SIMD is net-negative: barrier-locked waves stall in
// lockstep, so extra occupancy hides ~130cy but duplicates ~270cy overhead.)
#define FPS_T 256
#define FPS_PAIRS 8            // 8 float2-pairs = 16 points per thread

typedef float vf2 __attribute__((ext_vector_type(2)));

// ---------------------------------------------------------------------------
// Wave64 f32 max chain via DPP (full-rate, ~2cyc/stage issue).
// bound_ctrl=1 feeds 0.0 into invalid lanes — distances are >= 0 so 0 is a
// safe identity. After row_shr 1/2/4/8 + row_bcast 15/31, lane 63 = wave max.
// ---------------------------------------------------------------------------
template <int CTRL>
__device__ __forceinline__ float dpp_fmax(float x) {
    int t = __builtin_amdgcn_update_dpp(0, __float_as_int(x), CTRL, 0xF, 0xF, true);
    return fmaxf(x, __int_as_float(t));
}
__device__ __forceinline__ float wave_fmax63(float x) {
    x = dpp_fmax<0x111>(x);  // row_shr:1
    x = dpp_fmax<0x112>(x);  // row_shr:2
    x = dpp_fmax<0x114>(x);  // row_shr:4
    x = dpp_fmax<0x118>(x);  // row_shr:8
    x = dpp_fmax<0x142>(x);  // row_bcast:15
    x = dpp_fmax<0x143>(x);  // row_bcast:31
    return x;                 // valid in lane 63
}

// ---------------------------------------------------------------------------
// Kernel 1: transpose feature_map (B, C, N) -> fmT (B*N, C)
// (separate dispatch: r3 showed co-residency with FPS costs more in FPS
// contention (+24us) than the ~10us of transpose wall it hides)
// ---------------------------------------------------------------------------
__global__ void transpose_fm(const float* __restrict__ fm, float* __restrict__ fmT) {
    __shared__ float tile[32][33];
    const int b  = blockIdx.z;
    const int c0 = blockIdx.y * 32;
    const int n0 = blockIdx.x * 32;
    const int tx = threadIdx.x;   // 0..31
    const int ty = threadIdx.y;   // 0..7
    const float* p = fm + (size_t)b * C_SZ * N_SZ;
#pragma unroll
    for (int i = 0; i < 4; i++) {
        tile[ty + i * 8][tx] = p[(size_t)(c0 + ty + i * 8) * N_SZ + n0 + tx];
    }
    __syncthreads();
    float* q = fmT + (size_t)b * N_SZ * C_SZ;
#pragma unroll
    for (int i = 0; i < 4; i++) {
        q[(size_t)(n0 + ty + i * 8) * C_SZ + c0 + tx] = tile[tx][ty + i * 8];
    }
}

// ---------------------------------------------------------------------------
// Kernel 2: FPS, one block (256 threads, 4 waves — one per SIMD) per batch.
// Bit-exact numpy semantics: d=((x-cx)^2+(y-cy)^2)+(z-cz)^2 per-op rounding
// (contract/reassoc off), min then FIRST-index argmax.
//
// Tail structure (round 5): the winning lane publishes BOTH its u64 key
// (dist<<32 | 4095-n) and its candidate coords, selected from its OWN
// px/py/pz registers via a compile-time cndmask tree (depends only on bj,
// so it fills the DPP-chain stall slack — off the critical chain). This
// removes the dependent post-barrier sp[ci] read (~140cy serial) that r0
// paid. No readlane(bn)/coord readlanes needed: lane==first writes its own
// values. Post-barrier: 6 independent BROADCAST ds_reads (keys+coords,
// conflict-free) + cmp/cndmask tree. One barrier per iteration (parity
// double-buffer). No global traffic in the loop.
//
// History: r1 per-lane SCATTER sp[bn] read = 422k bank-conflict cycles
// (the structure was right, the scatter was the bug — fixed here with
// register selection); r2 v_pk asm = throughput-neutral; r3 transpose
// co-residency = contention; r4 2 waves/SIMD = lockstep, no hiding.
// ---------------------------------------------------------------------------
__global__ __launch_bounds__(FPS_T) void fps_kernel(
        const float* __restrict__ verts,   // (B, 3, N)
        float* __restrict__ out_vp,        // (B, 3, NPOINT)
        int* __restrict__ cents)           // (B, NPOINT)
{
#pragma clang fp contract(off)
#pragma clang fp reassociate(off)
    __shared__ float4 sp[N_SZ];                       // 64 KB xyz (w unused)
    __shared__ int    scent[NPOINT];                  //  4 KB
    __shared__ alignas(16) unsigned long long ckey[2][4];
    __shared__ alignas(16) float4 ccoord[2][4];

    const int b    = blockIdx.x;
    const int tid  = threadIdx.x;
    const int lane = tid & 63;
    const int wid  = tid >> 6;
    const float* vb = verts + (size_t)b * 3 * N_SZ;

    // stage xyz into LDS (coalesced global loads, conflict-free LDS writes)
    for (int n = tid; n < N_SZ; n += FPS_T) {
        sp[n] = make_float4(vb[n], vb[N_SZ + n], vb[2 * N_SZ + n], 0.0f);
    }

    // contiguous per-thread register copy via coalesced float4 loads
    const float4* vx4 = (const float4*)vb;
    const float4* vy4 = (const float4*)(vb + N_SZ);
    const float4* vz4 = (const float4*)(vb + 2 * N_SZ);
    vf2 px[FPS_PAIRS], py[FPS_PAIRS], pz[FPS_PAIRS], dd[FPS_PAIRS];
#pragma unroll
    for (int k = 0; k < 4; k++) {
        const float4 x = vx4[tid * 4 + k];
        const float4 y = vy4[tid * 4 + k];
        const float4 z = vz4[tid * 4 + k];
        px[2 * k] = (vf2){x.x, x.y}; px[2 * k + 1] = (vf2){x.z, x.w};
        py[2 * k] = (vf2){y.x, y.y}; py[2 * k + 1] = (vf2){y.z, y.w};
        pz[2 * k] = (vf2){z.x, z.y}; pz[2 * k + 1] = (vf2){z.z, z.w};
        dd[2 * k]     = (vf2){1e10f, 1e10f};
        dd[2 * k + 1] = (vf2){1e10f, 1e10f};
    }
    __syncthreads();

    int ci = 0;
    const float4 c0 = sp[0];
    float cx = c0.x, cy = c0.y, cz = c0.z;

    for (int i = 0; i < NPOINT; i++) {
        if (tid == 0) scent[i] = ci;

        const vf2 cx2 = (vf2){cx, cx};
        const vf2 cy2 = (vf2){cy, cy};
        const vf2 cz2 = (vf2){cz, cz};

        float m = -1.0f;                   // running max (v_max3 per pair)
#pragma unroll
        for (int p = 0; p < FPS_PAIRS; p++) {
            const vf2 dx = px[p] - cx2;
            const vf2 dy = py[p] - cy2;
            const vf2 dz = pz[p] - cz2;
            vf2 s = dx * dx + dy * dy;     // contract off => mul,mul,add
            s = s + dz * dz;               // ((x^2+y^2)+z^2) order
            vf2 d;
            d.x = fminf(dd[p].x, s.x);
            d.y = fminf(dd[p].y, s.y);
            dd[p] = d;
            m = fmaxf(m, fmaxf(d.x, d.y)); // folds to v_max3_f32
        }
        const float bv = m;

        // reverse scan: lowest j with dd[j] == bv (max is a selection =>
        // exact bitwise compare); n = tid*16 + j so min j == min n in-lane
        int bj = 0;
#pragma unroll
        for (int j = 15; j >= 0; j--) {
            const float v = (j & 1) ? dd[j >> 1].y : dd[j >> 1].x;
            if (v == bv) bj = j;
        }
        const int bn = (tid << 4) | bj;    // global point index

        // candidate coords from OWN registers: compile-time-indexed cndmask
        // tree (45 selects). Depends only on bj -> schedules into the DPP
        // chain's stall slack. NO LDS scatter (r1's 422k-conflict mistake).
        const bool half = (bj & 1) != 0;
        const int  bp   = bj >> 1;
        float hx[8], hy[8], hz[8];
#pragma unroll
        for (int p2 = 0; p2 < 8; p2++) {
            hx[p2] = half ? px[p2].y : px[p2].x;
            hy[p2] = half ? py[p2].y : py[p2].x;
            hz[p2] = half ? pz[p2].y : pz[p2].x;
        }
        const bool s0 = (bp & 1) != 0, s1 = (bp & 2) != 0, s2 = (bp & 4) != 0;
        const float ax0 = s0 ? hx[1] : hx[0], ax1 = s0 ? hx[3] : hx[2];
        const float ax2 = s0 ? hx[5] : hx[4], ax3 = s0 ? hx[7] : hx[6];
        const float ay0 = s0 ? hy[1] : hy[0], ay1 = s0 ? hy[3] : hy[2];
        const float ay2 = s0 ? hy[5] : hy[4], ay3 = s0 ? hy[7] : hy[6];
        const float az0 = s0 ? hz[1] : hz[0], az1 = s0 ? hz[3] : hz[2];
        const float az2 = s0 ? hz[5] : hz[4], az3 = s0 ? hz[7] : hz[6];
        const float bx0 = s1 ? ax1 : ax0, bx1 = s1 ? ax3 : ax2;
        const float by0 = s1 ? ay1 : ay0, by1 = s1 ? ay3 : ay2;
        const float bz0 = s1 ? az1 : az0, bz1 = s1 ? az3 : az2;
        const float candx = s2 ? bx1 : bx0;
        const float candy = s2 ? by1 : by0;
        const float candz = s2 ? bz1 : bz0;

        // wave argmax: f32 DPP chain + ballot; winning lane self-identifies
        const float wm = wave_fmax63(bv);
        const float wmax = __int_as_float(
            __builtin_amdgcn_readlane(__float_as_int(wm), 63));
        const unsigned long long mask = __ballot(bv == wmax);
        const int first = __ffsll(mask) - 1;

        const int par = i & 1;
        if (lane == first) {               // unique lane; writes OWN key+coords
            ckey[par][wid] = ((unsigned long long)__float_as_uint(bv) << 32) |
                             (unsigned long long)(4095u - (unsigned)bn);
            ccoord[par][wid] = make_float4(candx, candy, candz, 0.0f);
        }
        __syncthreads();

        // all threads redundantly resolve the 4-way final (no 2nd barrier:
        // parity double-buffer makes the next write race-free). 6 independent
        // BROADCAST ds_reads -> one latency window; cmp/cndmask tree; no
        // dependent sp[ci] fetch afterwards.
        const ulonglong2* kb = (const ulonglong2*)(&ckey[par][0]);
        const ulonglong2 k01 = kb[0], k23 = kb[1];
        const float4* qp = &ccoord[par][0];
        const float4 q0 = qp[0], q1 = qp[1], q2 = qp[2], q3 = qp[3];

        // ties impossible across waves (distinct index bits) -> strict >
        const bool t01 = k01.y > k01.x;
        const unsigned long long ka = t01 ? k01.y : k01.x;
        const float ax = t01 ? q1.x : q0.x;
        const float ay = t01 ? q1.y : q0.y;
        const float az = t01 ? q1.z : q0.z;

        const bool t23 = k23.y > k23.x;
        const unsigned long long kc = t23 ? k23.y : k23.x;
        const float bx = t23 ? q3.x : q2.x;
        const float by = t23 ? q3.y : q2.y;
        const float bz = t23 ? q3.z : q2.z;

        const bool tf = kc > ka;
        const unsigned long long kk = tf ? kc : ka;
        ci = (int)(4095u - (unsigned)kk);
        cx = tf ? bx : ax;
        cy = tf ? by : ay;
        cz = tf ? bz : az;
    }
    __syncthreads();

    // epilogue: coalesced writes of cents + vertices_pool
    for (int i = tid; i < NPOINT; i += FPS_T) {
        const int cc = scent[i];
        const float4 v = sp[cc];
        cents[b * NPOINT + i] = cc;
        out_vp[(b * 3 + 0) * NPOINT + i] = v.x;
        out_vp[(b * 3 + 1) * NPOINT + i] = v.y;
        out_vp[(b * 3 + 2) * NPOINT + i] = v.z;
    }
}

// ---------------------------------------------------------------------------
// Kernel 3: gather+maxpool selected rows AND transpose to (B, C, NPOINT).
// 16 waves per block; wave w pools point j0+w (64 lanes x float2 = 128 ch),
// stages the 16x128 tile in LDS, then writes channel-major 64B segments.
// ---------------------------------------------------------------------------
#define GT_J 16
__global__ __launch_bounds__(1024) void pool_gather_t(
        const float* __restrict__ fmT,     // (B*N, C)
        const int* __restrict__ idx,       // (B*N*K), values in [0, B*N)
        const int* __restrict__ cents,     // (B*NPOINT)
        float* __restrict__ out_fp)        // (B, C, NPOINT)
{
    __shared__ float tile[C_SZ][GT_J + 1];
    const int tid  = threadIdx.x;
    const int lane = tid & 63;
    const int w    = tid >> 6;
    const int j0   = blockIdx.x * GT_J;    // global pooled-point base
    const int gp   = j0 + w;
    const int b    = gp >> 10;             // NPOINT = 1024
    const int ci   = cents[gp];
    const int* ip  = idx + ((size_t)(b * N_SZ + ci)) * K_SZ;
    const float2* src = (const float2*)fmT;

    float2 acc = make_float2(-INFINITY, -INFINITY);
#pragma unroll
    for (int k = 0; k < K_SZ; k++) {
        const int p = ip[k];
        const float2 v = src[(size_t)p * (C_SZ / 2) + lane];
        acc.x = fmaxf(acc.x, v.x);
        acc.y = fmaxf(acc.y, v.y);
    }
    tile[2 * lane][w]     = acc.x;
    tile[2 * lane + 1][w] = acc.y;
    __syncthreads();

    float* q = out_fp + (size_t)b * C_SZ * NPOINT + (j0 & (NPOINT - 1));
#pragma unroll
    for (int it = 0; it < 2; it++) {
        const int e  = tid + it * 1024;
        const int c  = e >> 4;
        const int jj = e & (GT_J - 1);
        q[(size_t)c * NPOINT + jj] = tile[c][jj];
    }
}

// ---------------------------------------------------------------------------
extern "C" void kernel_launch(void* const* d_in, const int* in_sizes, int n_in,
                              void* d_out, int out_size, void* d_ws, size_t ws_size,
                              hipStream_t stream) {
    const float* verts = (const float*)d_in[0];   // (B,3,N) f32
    const float* fm    = (const float*)d_in[1];   // (B,C,N) f32
    const int*   idx   = (const int*)d_in[2];     // (B*N*K) i32

    float* out    = (float*)d_out;
    float* out_vp = out;                               // B*3*NPOINT = 24576
    float* out_fp = out + (size_t)B_SZ * 3 * NPOINT;   // B*C*NPOINT

    char* ws = (char*)d_ws;
    float* fmT   = (float*)ws;                                     // 16 MB
    int*   cents = (int*)(ws + (size_t)B_SZ * N_SZ * C_SZ * 4);    // 32 KB

    dim3 tb(32, 8);
    transpose_fm<<<dim3(N_SZ / 32, C_SZ / 32, B_SZ), tb, 0, stream>>>(fm, fmT);
    fps_kernel<<<B_SZ, FPS_T, 0, stream>>>(verts, out_vp, cents);
    pool_gather_t<<<(B_SZ * NPOINT) / GT_J, 1024, 0, stream>>>(fmT, idx, cents, out_fp);
}

// Round 6
// 622.611 us; speedup vs baseline: 1.8308x; 1.8308x over previous
//
#include <hip/hip_runtime.h>
#include <hip/hip_bf16.h>
#include <math.h>

// Problem constants
#define B_SZ 8
#define N_SZ 4096
#define C_SZ 128
#define K_SZ 16
#define NPOINT 1024            // N / POOL_RATE

// FPS config: 256 threads (4 waves, 1 per SIMD), 16 CONTIGUOUS points/thread
#define FPS_T 256
#define FPS_PAIRS 8            // 8 float2-pairs = 16 points per thread

typedef float vf2 __attribute__((ext_vector_type(2)));

// ---------------------------------------------------------------------------
// Wave64 f32 max chain via DPP (full-rate, ~2cyc/stage issue).
// bound_ctrl=1 feeds 0.0 into invalid lanes — distances are >= 0 so 0 is a
// safe identity. After row_shr 1/2/4/8 + row_bcast 15/31, lane 63 = wave max.
// ---------------------------------------------------------------------------
template <int CTRL>
__device__ __forceinline__ float dpp_fmax(float x) {
    int t = __builtin_amdgcn_update_dpp(0, __float_as_int(x), CTRL, 0xF, 0xF, true);
    return fmaxf(x, __int_as_float(t));
}
__device__ __forceinline__ float wave_fmax63(float x) {
    x = dpp_fmax<0x111>(x);  // row_shr:1
    x = dpp_fmax<0x112>(x);  // row_shr:2
    x = dpp_fmax<0x114>(x);  // row_shr:4
    x = dpp_fmax<0x118>(x);  // row_shr:8
    x = dpp_fmax<0x142>(x);  // row_bcast:15
    x = dpp_fmax<0x143>(x);  // row_bcast:31
    return x;                 // valid in lane 63
}
__device__ __forceinline__ unsigned long long kmax2(unsigned long long a,
                                                   unsigned long long b) {
    return a > b ? a : b;
}

// ---------------------------------------------------------------------------
// Merged kernel: blocks 0..7 run FPS (one per batch); blocks 8..8+4095 run
// the feature-map transpose (B,C,N)->(B*N,C).
//
// KEY vs round 3 (which regressed fps 529->553): the union carries an 86016B
// pad, so LDS_Block_Size = 86016 and 2*86016 > 160KB -> the HW CANNOT place
// a transpose block on a CU hosting an fps block. r3's counters proved the
// contention was co-residency (Occupancy 0.38 -> 0.63-0.76); this forces
// 1 block/CU, so transpose runs only on the ~248 idle CUs, fully hidden
// under fps's 529us shadow (transpose total work ~11us of wall).
//
// FPS body is byte-for-byte round 0 (the proven 529us loop). Bit-exact
// numpy semantics: d=((x-cx)^2+(y-cy)^2)+(z-cz)^2 per-op rounding
// (contract/reassoc off), min then FIRST-index argmax.
//  * thread tid owns contiguous points [tid*16, tid*16+16): lane order ==
//    point order, so wave argmax = f32 DPP chain -> readlane(63) ->
//    ballot(bv==wmax) -> s_ff1 -> readlane(bn, first) (min n among ties).
//  * cross-wave: packed u64 key (dist<<32)|(4095-n); max => max d, min n.
//    Parity double-buffered ckey => ONE barrier per iteration.
//  * post-barrier sp[ci] read is a BROADCAST (conflict-free).
//
// Failed-experiment ledger (do not retry): r1 per-lane scatter sp[bn] read
// = 422k bank-conflict cycles; r2 v_pk asm = throughput-neutral + marshaling
// (pk f32 is 4cyc occupancy vs 2cyc scalar, same FLOPs/cyc); r3 co-residency
// contention (fixed here via LDS exclusivity); r4 2 waves/SIMD = barrier-
// lockstep, duplicated overhead > hidden latency; r5 register cndmask-tree
// coords = pathological schedule (stall/iter tripled).
// ---------------------------------------------------------------------------
union SMem {
    struct {
        float4 sp[N_SZ];                       // 64 KB xyz (w unused)
        int    scent[NPOINT];                  //  4 KB
        unsigned long long ckey[2][4];         // parity double-buffer
    } f;
    float tile[32][33];                        // transpose tile
    char  pad[86016];                          // force 1 block/CU (2x > 160KB)
};

__global__ __launch_bounds__(FPS_T) void fps_tr_kernel(
        const float* __restrict__ verts,   // (B, 3, N)
        const float* __restrict__ fm,      // (B, C, N)
        float* __restrict__ out_vp,        // (B, 3, NPOINT)
        int* __restrict__ cents,           // (B, NPOINT)
        float* __restrict__ fmT)           // (B*N, C)
{
#pragma clang fp contract(off)
#pragma clang fp reassociate(off)
    __shared__ SMem sm;
    const int tid = threadIdx.x;

    if (blockIdx.x >= B_SZ) {
        // ---------------- transpose path (4096 blocks) ----------------
        const int bid = blockIdx.x - B_SZ;       // original grid (128,4,8)
        const int n0 = (bid & 127) * 32;
        const int c0 = ((bid >> 7) & 3) * 32;
        const int b  = bid >> 9;
        const int tx = tid & 31;                 // 0..31
        const int ty = tid >> 5;                 // 0..7
        const float* p = fm + (size_t)b * C_SZ * N_SZ;
#pragma unroll
        for (int i = 0; i < 4; i++) {
            sm.tile[ty + i * 8][tx] =
                p[(size_t)(c0 + ty + i * 8) * N_SZ + n0 + tx];
        }
        __syncthreads();
        float* q = fmT + (size_t)b * N_SZ * C_SZ;
#pragma unroll
        for (int i = 0; i < 4; i++) {
            q[(size_t)(n0 + ty + i * 8) * C_SZ + c0 + tx] =
                sm.tile[tx][ty + i * 8];
        }
        return;
    }

    // ------------------------- FPS path (8 blocks) -------------------------
    float4* sp   = sm.f.sp;
    int*    scnt = sm.f.scent;

    const int b    = blockIdx.x;
    const int lane = tid & 63;
    const int wid  = tid >> 6;
    const float* vb = verts + (size_t)b * 3 * N_SZ;

    // stage xyz into LDS (coalesced global loads, conflict-free LDS writes)
    for (int n = tid; n < N_SZ; n += FPS_T) {
        sp[n] = make_float4(vb[n], vb[N_SZ + n], vb[2 * N_SZ + n], 0.0f);
    }

    // contiguous per-thread register copy via coalesced float4 loads
    const float4* vx4 = (const float4*)vb;
    const float4* vy4 = (const float4*)(vb + N_SZ);
    const float4* vz4 = (const float4*)(vb + 2 * N_SZ);
    vf2 px[FPS_PAIRS], py[FPS_PAIRS], pz[FPS_PAIRS], dd[FPS_PAIRS];
#pragma unroll
    for (int k = 0; k < 4; k++) {
        const float4 x = vx4[tid * 4 + k];
        const float4 y = vy4[tid * 4 + k];
        const float4 z = vz4[tid * 4 + k];
        px[2 * k] = (vf2){x.x, x.y}; px[2 * k + 1] = (vf2){x.z, x.w};
        py[2 * k] = (vf2){y.x, y.y}; py[2 * k + 1] = (vf2){y.z, y.w};
        pz[2 * k] = (vf2){z.x, z.y}; pz[2 * k + 1] = (vf2){z.z, z.w};
        dd[2 * k]     = (vf2){1e10f, 1e10f};
        dd[2 * k + 1] = (vf2){1e10f, 1e10f};
    }
    __syncthreads();

    int ci = 0;
    const float4 c0 = sp[0];
    float cx = c0.x, cy = c0.y, cz = c0.z;

    for (int i = 0; i < NPOINT; i++) {
        if (tid == 0) scnt[i] = ci;

        const vf2 cx2 = (vf2){cx, cx};
        const vf2 cy2 = (vf2){cy, cy};
        const vf2 cz2 = (vf2){cz, cz};

        float m = -1.0f;                   // running max (v_max3 per pair)
#pragma unroll
        for (int p = 0; p < FPS_PAIRS; p++) {
            const vf2 dx = px[p] - cx2;
            const vf2 dy = py[p] - cy2;
            const vf2 dz = pz[p] - cz2;
            vf2 s = dx * dx + dy * dy;     // contract off => mul,mul,add
            s = s + dz * dz;               // ((x^2+y^2)+z^2) order
            vf2 d;
            d.x = fminf(dd[p].x, s.x);
            d.y = fminf(dd[p].y, s.y);
            dd[p] = d;
            m = fmaxf(m, fmaxf(d.x, d.y)); // folds to v_max3_f32
        }
        const float bv = m;

        // reverse scan: lowest j with dd[j] == bv (max is a selection =>
        // exact bitwise compare); n = tid*16 + j so min j == min n in-lane
        int bj = 0;
#pragma unroll
        for (int j = 15; j >= 0; j--) {
            const float v = (j & 1) ? dd[j >> 1].y : dd[j >> 1].x;
            if (v == bv) bj = j;
        }
        const int bn = (tid << 4) | bj;    // global point index

        // wave argmax: f32 chain + ballot + first-lane readback
        const float wm = wave_fmax63(bv);
        const float wmax = __int_as_float(
            __builtin_amdgcn_readlane(__float_as_int(wm), 63));
        const unsigned long long mask = __ballot(bv == wmax);
        const int first = __ffsll(mask) - 1;
        const unsigned nw = (unsigned)__builtin_amdgcn_readlane(bn, first);

        const unsigned long long wkey =
            ((unsigned long long)__float_as_uint(wmax) << 32) |
            (unsigned long long)(4095u - nw);

        const int par = i & 1;
        if (lane == 0) sm.f.ckey[par][wid] = wkey;
        __syncthreads();

        // all threads redundantly resolve the 4-way final (no 2nd barrier:
        // parity double-buffer makes the next write race-free)
        const ulonglong2* kb = (const ulonglong2*)(&sm.f.ckey[par][0]);
        const ulonglong2 k01 = kb[0], k23 = kb[1];
        const unsigned long long kk =
            kmax2(kmax2(k01.x, k01.y), kmax2(k23.x, k23.y));

        ci = (int)(4095u - (unsigned)kk);
        const float4 c = sp[ci];           // broadcast read: conflict-free
        cx = c.x; cy = c.y; cz = c.z;
    }
    __syncthreads();

    // epilogue: coalesced writes of cents + vertices_pool
    for (int i = tid; i < NPOINT; i += FPS_T) {
        const int cc = scnt[i];
        const float4 v = sp[cc];
        cents[b * NPOINT + i] = cc;
        out_vp[(b * 3 + 0) * NPOINT + i] = v.x;
        out_vp[(b * 3 + 1) * NPOINT + i] = v.y;
        out_vp[(b * 3 + 2) * NPOINT + i] = v.z;
    }
}

// ---------------------------------------------------------------------------
// Kernel 2: gather+maxpool selected rows AND transpose to (B, C, NPOINT).
// 16 waves per block; wave w pools point j0+w (64 lanes x float2 = 128 ch),
// stages the 16x128 tile in LDS, then writes channel-major 64B segments.
// ---------------------------------------------------------------------------
#define GT_J 16
__global__ __launch_bounds__(1024) void pool_gather_t(
        const float* __restrict__ fmT,     // (B*N, C)
        const int* __restrict__ idx,       // (B*N*K), values in [0, B*N)
        const int* __restrict__ cents,     // (B*NPOINT)
        float* __restrict__ out_fp)        // (B, C, NPOINT)
{
    __shared__ float tile[C_SZ][GT_J + 1];
    const int tid  = threadIdx.x;
    const int lane = tid & 63;
    const int w    = tid >> 6;
    const int j0   = blockIdx.x * GT_J;    // global pooled-point base
    const int gp   = j0 + w;
    const int b    = gp >> 10;             // NPOINT = 1024
    const int ci   = cents[gp];
    const int* ip  = idx + ((size_t)(b * N_SZ + ci)) * K_SZ;
    const float2* src = (const float2*)fmT;

    float2 acc = make_float2(-INFINITY, -INFINITY);
#pragma unroll
    for (int k = 0; k < K_SZ; k++) {
        const int p = ip[k];
        const float2 v = src[(size_t)p * (C_SZ / 2) + lane];
        acc.x = fmaxf(acc.x, v.x);
        acc.y = fmaxf(acc.y, v.y);
    }
    tile[2 * lane][w]     = acc.x;
    tile[2 * lane + 1][w] = acc.y;
    __syncthreads();

    float* q = out_fp + (size_t)b * C_SZ * NPOINT + (j0 & (NPOINT - 1));
#pragma unroll
    for (int it = 0; it < 2; it++) {
        const int e  = tid + it * 1024;
        const int c  = e >> 4;
        const int jj = e & (GT_J - 1);
        q[(size_t)c * NPOINT + jj] = tile[c][jj];
    }
}

// ---------------------------------------------------------------------------
extern "C" void kernel_launch(void* const* d_in, const int* in_sizes, int n_in,
                              void* d_out, int out_size, void* d_ws, size_t ws_size,
                              hipStream_t stream) {
    const float* verts = (const float*)d_in[0];   // (B,3,N) f32
    const float* fm    = (const float*)d_in[1];   // (B,C,N) f32
    const int*   idx   = (const int*)d_in[2];     // (B*N*K) i32

    float* out    = (float*)d_out;
    float* out_vp = out;                               // B*3*NPOINT = 24576
    float* out_fp = out + (size_t)B_SZ * 3 * NPOINT;   // B*C*NPOINT

    char* ws = (char*)d_ws;
    float* fmT   = (float*)ws;                                     // 16 MB
    int*   cents = (int*)(ws + (size_t)B_SZ * N_SZ * C_SZ * 4);    // 32 KB

    // FPS blocks 0..7 + transpose blocks 8..4103 in one dispatch; 86KB LDS
    // per block guarantees no CU hosts two blocks -> transpose never touches
    // the 8 fps CUs, running hidden on the other ~248.
    fps_tr_kernel<<<B_SZ + (N_SZ / 32) * (C_SZ / 32) * B_SZ, FPS_T, 0, stream>>>(
        verts, fm, out_vp, cents, fmT);
    pool_gather_t<<<(B_SZ * NPOINT) / GT_J, 1024, 0, stream>>>(fmT, idx, cents, out_fp);
}

// Round 7
// 612.886 us; speedup vs baseline: 1.8598x; 1.0159x over previous
//
#include <hip/hip_runtime.h>
#include <hip/hip_bf16.h>
#include <math.h>

// Problem constants
#define B_SZ 8
#define N_SZ 4096
#define C_SZ 128
#define K_SZ 16
#define NPOINT 1024            // N / POOL_RATE

// FPS config: 256 threads (4 waves, 1 per SIMD), 16 CONTIGUOUS points/thread
#define FPS_T 256
#define FPS_PAIRS 8            // 8 float2-pairs = 16 points per thread

typedef float vf2 __attribute__((ext_vector_type(2)));

// ---------------------------------------------------------------------------
// Wave64 f32 max chain via DPP (full-rate, ~2cyc/stage issue).
// bound_ctrl=1 feeds 0.0 into invalid lanes — distances are >= 0 so 0 is a
// safe identity. After row_shr 1/2/4/8 + row_bcast 15/31, lane 63 = wave max.
// ---------------------------------------------------------------------------
template <int CTRL>
__device__ __forceinline__ float dpp_fmax(float x) {
    int t = __builtin_amdgcn_update_dpp(0, __float_as_int(x), CTRL, 0xF, 0xF, true);
    return fmaxf(x, __int_as_float(t));
}
__device__ __forceinline__ float wave_fmax63(float x) {
    x = dpp_fmax<0x111>(x);  // row_shr:1
    x = dpp_fmax<0x112>(x);  // row_shr:2
    x = dpp_fmax<0x114>(x);  // row_shr:4
    x = dpp_fmax<0x118>(x);  // row_shr:8
    x = dpp_fmax<0x142>(x);  // row_bcast:15
    x = dpp_fmax<0x143>(x);  // row_bcast:31
    return x;                 // valid in lane 63
}
__device__ __forceinline__ unsigned long long kmax2(unsigned long long a,
                                                   unsigned long long b) {
    return a > b ? a : b;
}

// ---------------------------------------------------------------------------
// Kernel 1: transpose feature_map (B, C, N) -> fmT (B*N, C), float4 both
// sides (4x fewer global instructions than the scalar 32x32 version).
// Thread (ty=tid>>3 in 0..31, tx=tid&7): loads float4 along N, stores
// float4 along C. LDS tile[32][33]: ~2-way conflicts max (free).
// ---------------------------------------------------------------------------
__global__ __launch_bounds__(256) void transpose_fm(
        const float* __restrict__ fm, float* __restrict__ fmT) {
    __shared__ float tile[32][33];
    const int b  = blockIdx.z;
    const int c0 = blockIdx.y * 32;
    const int n0 = blockIdx.x * 32;
    const int tx = threadIdx.x & 7;    // float4 group 0..7
    const int ty = threadIdx.x >> 3;   // row 0..31
    const float* p = fm + (size_t)b * C_SZ * N_SZ;

    const float4 v = ((const float4*)(p + (size_t)(c0 + ty) * N_SZ + n0))[tx];
    tile[ty][4 * tx + 0] = v.x;
    tile[ty][4 * tx + 1] = v.y;
    tile[ty][4 * tx + 2] = v.z;
    tile[ty][4 * tx + 3] = v.w;
    __syncthreads();

    float* q = fmT + (size_t)b * N_SZ * C_SZ;
    float4 o;
    o.x = tile[4 * tx + 0][ty];
    o.y = tile[4 * tx + 1][ty];
    o.z = tile[4 * tx + 2][ty];
    o.w = tile[4 * tx + 3][ty];
    ((float4*)(q + (size_t)(n0 + ty) * C_SZ + c0))[tx] = o;
}

// ---------------------------------------------------------------------------
// Kernel 2: FPS — BYTE-FOR-BYTE round 0 (529.6us, the proven floor).
// Bit-exact numpy semantics: d=((x-cx)^2+(y-cy)^2)+(z-cz)^2 per-op rounding
// (contract/reassoc off), min then FIRST-index argmax.
//
// Layout: thread tid owns contiguous points [tid*16, tid*16+16). Hence
// within a wave, lane order == point-index order, so the wave argmax is:
//   f32 DPP max chain -> readlane(63) -> ballot(bv==wmax) -> s_ff1 ->
//   readlane(n, first_lane)   (min n among ties, exact)
// Per-lane reverse scan gives min j (= min n) within the lane.
// Cross-wave: packed u64 key (dist<<32)|(4095-n), max => max dist, min n.
// One barrier per iteration; no global traffic in the loop.
//
// DO-NOT-RETRY ledger: r1 per-lane scatter sp[bn] read = 422k bank-conflict
// cycles; r2 v_pk asm = throughput-neutral (pk f32 = 4cyc occupancy vs 2cyc
// scalar, same FLOPs/cyc) + marshaling; r3/r6 transpose-merge = +24us on fps
// regardless of co-residency (proven by r6's LDS-exclusivity A/B); r4
// 2 waves/SIMD = barrier-lockstep, duplicated overhead > hidden latency;
// r5 register cndmask-tree coords = pathological schedule (stalls 3x).
// ---------------------------------------------------------------------------
__global__ __launch_bounds__(FPS_T) void fps_kernel(
        const float* __restrict__ verts,   // (B, 3, N)
        float* __restrict__ out_vp,        // (B, 3, NPOINT)
        int* __restrict__ cents)           // (B, NPOINT)
{
#pragma clang fp contract(off)
#pragma clang fp reassociate(off)
    __shared__ float4 sp[N_SZ];                       // 64 KB xyz (w unused)
    __shared__ int    scent[NPOINT];                  //  4 KB
    __shared__ alignas(16) unsigned long long ckey[2][4];

    const int b    = blockIdx.x;
    const int tid  = threadIdx.x;
    const int lane = tid & 63;
    const int wid  = tid >> 6;
    const float* vb = verts + (size_t)b * 3 * N_SZ;

    // stage xyz into LDS (coalesced global loads, conflict-free LDS writes)
    for (int n = tid; n < N_SZ; n += FPS_T) {
        sp[n] = make_float4(vb[n], vb[N_SZ + n], vb[2 * N_SZ + n], 0.0f);
    }

    // contiguous per-thread register copy via coalesced float4 loads
    const float4* vx4 = (const float4*)vb;
    const float4* vy4 = (const float4*)(vb + N_SZ);
    const float4* vz4 = (const float4*)(vb + 2 * N_SZ);
    vf2 px[FPS_PAIRS], py[FPS_PAIRS], pz[FPS_PAIRS], dd[FPS_PAIRS];
#pragma unroll
    for (int k = 0; k < 4; k++) {
        const float4 x = vx4[tid * 4 + k];
        const float4 y = vy4[tid * 4 + k];
        const float4 z = vz4[tid * 4 + k];
        px[2 * k] = (vf2){x.x, x.y}; px[2 * k + 1] = (vf2){x.z, x.w};
        py[2 * k] = (vf2){y.x, y.y}; py[2 * k + 1] = (vf2){y.z, y.w};
        pz[2 * k] = (vf2){z.x, z.y}; pz[2 * k + 1] = (vf2){z.z, z.w};
        dd[2 * k]     = (vf2){1e10f, 1e10f};
        dd[2 * k + 1] = (vf2){1e10f, 1e10f};
    }
    __syncthreads();

    int ci = 0;
    const float4 c0 = sp[0];
    float cx = c0.x, cy = c0.y, cz = c0.z;

    for (int i = 0; i < NPOINT; i++) {
        if (tid == 0) scent[i] = ci;

        const vf2 cx2 = (vf2){cx, cx};
        const vf2 cy2 = (vf2){cy, cy};
        const vf2 cz2 = (vf2){cz, cz};

        float m = -1.0f;                   // running max (v_max3 per pair)
#pragma unroll
        for (int p = 0; p < FPS_PAIRS; p++) {
            const vf2 dx = px[p] - cx2;
            const vf2 dy = py[p] - cy2;
            const vf2 dz = pz[p] - cz2;
            vf2 s = dx * dx + dy * dy;     // contract off => mul,mul,add
            s = s + dz * dz;               // ((x^2+y^2)+z^2) order
            vf2 d;
            d.x = fminf(dd[p].x, s.x);
            d.y = fminf(dd[p].y, s.y);
            dd[p] = d;
            m = fmaxf(m, fmaxf(d.x, d.y)); // folds to v_max3_f32
        }
        const float bv = m;

        // reverse scan: lowest j with dd[j] == bv (max is a selection =>
        // exact bitwise compare); n = tid*16 + j so min j == min n in-lane
        int bj = 0;
#pragma unroll
        for (int j = 15; j >= 0; j--) {
            const float v = (j & 1) ? dd[j >> 1].y : dd[j >> 1].x;
            if (v == bv) bj = j;
        }
        const int bn = (tid << 4) | bj;    // global point index

        // wave argmax: f32 chain + ballot + first-lane readback
        const float wm = wave_fmax63(bv);
        const float wmax = __int_as_float(
            __builtin_amdgcn_readlane(__float_as_int(wm), 63));
        const unsigned long long mask = __ballot(bv == wmax);
        const int first = __ffsll(mask) - 1;
        const unsigned nw = (unsigned)__builtin_amdgcn_readlane(bn, first);

        const unsigned long long wkey =
            ((unsigned long long)__float_as_uint(wmax) << 32) |
            (unsigned long long)(4095u - nw);

        const int par = i & 1;
        if (lane == 0) ckey[par][wid] = wkey;
        __syncthreads();

        // all threads redundantly resolve the 4-way final (no 2nd barrier:
        // parity double-buffer makes the next write race-free)
        const ulonglong2* kb = (const ulonglong2*)(&ckey[par][0]);
        const ulonglong2 k01 = kb[0], k23 = kb[1];
        const unsigned long long kk =
            kmax2(kmax2(k01.x, k01.y), kmax2(k23.x, k23.y));

        ci = (int)(4095u - (unsigned)kk);
        const float4 c = sp[ci];           // broadcast read: conflict-free
        cx = c.x; cy = c.y; cz = c.z;
    }
    __syncthreads();

    // epilogue: coalesced writes of cents + vertices_pool
    for (int i = tid; i < NPOINT; i += FPS_T) {
        const int cc = scent[i];
        const float4 v = sp[cc];
        cents[b * NPOINT + i] = cc;
        out_vp[(b * 3 + 0) * NPOINT + i] = v.x;
        out_vp[(b * 3 + 1) * NPOINT + i] = v.y;
        out_vp[(b * 3 + 2) * NPOINT + i] = v.z;
    }
}

// ---------------------------------------------------------------------------
// Kernel 3: gather+maxpool selected rows AND transpose to (B, C, NPOINT).
// 16 waves per block; wave w pools point j0+w. float4 gathers: lane =
// (neighbor-half nb = lane>>5) x (channel-quad c4 = lane&31); 8 dwordx4
// loads cover 16 neighbors x 128 channels (16B/lane sweet spot — half the
// instructions of the float2 version). Halves combined via shfl_xor(32)
// (max is a selection — order-independent, bit-exact). Then the 16x128
// tile staging + channel-major writes as before.
// ---------------------------------------------------------------------------
#define GT_J 16
__global__ __launch_bounds__(1024) void pool_gather_t(
        const float* __restrict__ fmT,     // (B*N, C)
        const int* __restrict__ idx,       // (B*N*K), values in [0, B*N)
        const int* __restrict__ cents,     // (B*NPOINT)
        float* __restrict__ out_fp)        // (B, C, NPOINT)
{
    __shared__ float tile[C_SZ][GT_J + 1];
    const int tid  = threadIdx.x;
    const int lane = tid & 63;
    const int w    = tid >> 6;
    const int j0   = blockIdx.x * GT_J;    // global pooled-point base
    const int gp   = j0 + w;
    const int b    = gp >> 10;             // NPOINT = 1024
    const int ci   = cents[gp];
    const int* ip  = idx + ((size_t)(b * N_SZ + ci)) * K_SZ;
    const int nb   = lane >> 5;            // neighbor half: 0 or 1
    const int c4   = lane & 31;            // channel quad 0..31
    const float4* src = (const float4*)fmT;

    float4 acc = make_float4(-INFINITY, -INFINITY, -INFINITY, -INFINITY);
#pragma unroll
    for (int k = 0; k < K_SZ / 2; k++) {
        const int p = ip[2 * k + nb];
        const float4 v = src[(size_t)p * (C_SZ / 4) + c4];
        acc.x = fmaxf(acc.x, v.x);
        acc.y = fmaxf(acc.y, v.y);
        acc.z = fmaxf(acc.z, v.z);
        acc.w = fmaxf(acc.w, v.w);
    }
    // combine the two neighbor-halves (lane l <-> l^32), exact selection
    acc.x = fmaxf(acc.x, __shfl_xor(acc.x, 32, 64));
    acc.y = fmaxf(acc.y, __shfl_xor(acc.y, 32, 64));
    acc.z = fmaxf(acc.z, __shfl_xor(acc.z, 32, 64));
    acc.w = fmaxf(acc.w, __shfl_xor(acc.w, 32, 64));

    // both halves hold identical acc; each lane writes 2 of its 4 channels
    {
        const float e0 = nb ? acc.z : acc.x;
        const float e1 = nb ? acc.w : acc.y;
        tile[4 * c4 + 2 * nb + 0][w] = e0;
        tile[4 * c4 + 2 * nb + 1][w] = e1;
    }
    __syncthreads();

    float* q = out_fp + (size_t)b * C_SZ * NPOINT + (j0 & (NPOINT - 1));
#pragma unroll
    for (int it = 0; it < 2; it++) {
        const int e  = tid + it * 1024;
        const int c  = e >> 4;
        const int jj = e & (GT_J - 1);
        q[(size_t)c * NPOINT + jj] = tile[c][jj];
    }
}

// ---------------------------------------------------------------------------
extern "C" void kernel_launch(void* const* d_in, const int* in_sizes, int n_in,
                              void* d_out, int out_size, void* d_ws, size_t ws_size,
                              hipStream_t stream) {
    const float* verts = (const float*)d_in[0];   // (B,3,N) f32
    const float* fm    = (const float*)d_in[1];   // (B,C,N) f32
    const int*   idx   = (const int*)d_in[2];     // (B*N*K) i32

    float* out    = (float*)d_out;
    float* out_vp = out;                               // B*3*NPOINT = 24576
    float* out_fp = out + (size_t)B_SZ * 3 * NPOINT;   // B*C*NPOINT

    char* ws = (char*)d_ws;
    float* fmT   = (float*)ws;                                     // 16 MB
    int*   cents = (int*)(ws + (size_t)B_SZ * N_SZ * C_SZ * 4);    // 32 KB

    transpose_fm<<<dim3(N_SZ / 32, C_SZ / 32, B_SZ), 256, 0, stream>>>(fm, fmT);
    fps_kernel<<<B_SZ, FPS_T, 0, stream>>>(verts, out_vp, cents);
    pool_gather_t<<<(B_SZ * NPOINT) / GT_J, 1024, 0, stream>>>(fmT, idx, cents, out_fp);
}